// Round 8
// baseline (930.342 us; speedup 1.0000x reference)
//
// v7: 64x64 wave tile (128x128 block), slice-major conflict-free LDS,
//     LDS double-buffer (1 barrier/chunk), T14 depth-2 register prefetch.
#include <hip/hip_runtime.h>

#define TRIP 1533   // 3*511

typedef __attribute__((ext_vector_type(8))) short bf16x8;
typedef __attribute__((ext_vector_type(4))) float f32x4;

__device__ __forceinline__ void split2(float a, float b, unsigned& h, unsigned& l) {
    unsigned ba = __float_as_uint(a), bb = __float_as_uint(b);
    unsigned ha = ba & 0xFFFF0000u, hb = bb & 0xFFFF0000u;
    float ra = a - __uint_as_float(ha);
    float rb = b - __uint_as_float(hb);
    h = (ba >> 16) | hb;
    l = (__float_as_uint(ra) >> 16) | (__float_as_uint(rb) & 0xFFFF0000u);
}

// ---------------- W repack+split: WtHi/Lo[o][ks*CIN+c] = split(W[o][c][ks]) ----------------
template<int CIN, int COUT>
__global__ void k_repackW(const float* __restrict__ W,
                          unsigned short* __restrict__ Hi, unsigned short* __restrict__ Lo) {
    int id = blockIdx.x * 256 + threadIdx.x;
    if (id >= 3 * CIN * COUT) return;
    int o = id / (3 * CIN), kk = id % (3 * CIN);
    int ks = kk / CIN, c = kk % CIN;
    float v = W[(o * CIN + c) * 3 + ks];
    unsigned b = __float_as_uint(v);
    unsigned h = b & 0xFFFF0000u;
    float r = v - __uint_as_float(h);
    Hi[id] = (unsigned short)(b >> 16);
    Lo[id] = (unsigned short)(__float_as_uint(r) >> 16);
}

// ---------------- transpose trees [Bc][128][512] -> t0 [Bc][512][128] ----------------
__global__ void k_transpose(const float* __restrict__ in, float* __restrict__ out) {
    __shared__ float tl[64][129];
    int b = blockIdx.z, n0 = blockIdx.x * 64, t = threadIdx.x;
    int n = t & 63;
    for (int c = t >> 6; c < 128; c += 4)
        tl[n][c] = in[((size_t)b * 128 + c) * 512 + n0 + n];
    __syncthreads();
    int cq = t & 31;
    for (int nr = t >> 5; nr < 64; nr += 8) {
        float4 v = { tl[nr][cq*4+0], tl[nr][cq*4+1], tl[nr][cq*4+2], tl[nr][cq*4+3] };
        *(float4*)&out[((size_t)b * 512 + n0 + nr) * 128 + cq * 4] = v;
    }
}

// ---------------- zero node-0 row of activation buffers ----------------
__global__ void k_zero_row0(float* __restrict__ o1, float* __restrict__ o2, float* __restrict__ o3) {
    int b = blockIdx.x, t = threadIdx.x;
    if (t < 256) o1[(size_t)b * 512 * 256 + t] = 0.f;
    if (t < 128) o2[(size_t)b * 512 * 128 + t] = 0.f;
    if (t < 64)  o3[(size_t)b * 512 * 64  + t] = 0.f;
}

// ---------------- MFMA conv: Out[b][n][o] = sum_kk f(G)[n][kk] * W[kk][o] ----------------
// Block tile 128 nodes x OCH_T och; 4 waves (2 node-halves x 2 och-halves),
// wave tile 64 x OCH_T/2. LDS slice-major: [slice=k/8][row][8 bf16], pitch
// row*8+8 ushorts (16B slice stagger) -> conflict-free reads AND writes.
template<int CIN, int COUT, int OCH_T, bool NORM_IN>
__global__ __launch_bounds__(256, 2) void k_convmfma(
    const float* __restrict__ xin, const int* __restrict__ idx,
    const unsigned short* __restrict__ WHi, const unsigned short* __restrict__ WLo,
    const float* __restrict__ bias, float* __restrict__ out,
    const float* __restrict__ sIn, float* __restrict__ sOut)
{
    constexpr int K  = 3 * CIN;
    constexpr int NK = K / 32;
    constexpr int NI = OCH_T / 32;   // B frags per wave
    constexpr int OH = OCH_T / 2;    // wave och tile
    constexpr int GP = 128 * 8 + 8;  // G slice pitch (ushorts)
    constexpr int WP = OCH_T * 8 + 8;// W slice pitch

    __shared__ unsigned short Gh[2 * 4 * GP], Gl[2 * 4 * GP];
    __shared__ unsigned short Wh[2 * 4 * WP], Wl[2 * 4 * WP];
    __shared__ float rs[4], rq[4];

    const int b    = blockIdx.z;
    const int och0 = blockIdx.y * OCH_T;
    const int n0   = 1 + blockIdx.x * 128;
    const int t    = threadIdx.x;
    const int lane = t & 63, wave = t >> 6;
    const int wm = wave >> 1, wn = wave & 1;
    const int l15 = lane & 15, l16 = lane >> 4;

    float mean = 0.f, inv = 1.f;
    if (NORM_IN) {
        float s = sIn[b * 2], ss = sIn[b * 2 + 1];
        const float nel = (float)(CIN * 512);
        float mu  = s / nel;
        float var = (ss - nel * mu * mu) / (nel - 1.f);
        mean = mu; inv = 1.f / (sqrtf(var) + 1e-5f);
    }

    // staging roles: G: node = t&127, k-half = t>>7; W: och-row + k-half/slice
    const int nodeL = t & 127, ghalf = t >> 7, cb = ghalf * 16;
    int il0 = 0, il1 = 0, il2 = 0;
    if (n0 + nodeL <= 511) {
        const int* ip = &idx[b * TRIP + 3 * (n0 - 1 + nodeL)];
        il0 = ip[0]; il1 = ip[1]; il2 = ip[2];
    }
    const float* gBase = &xin[(size_t)b * 512 * CIN];

    float4 g0, g1, g2, g3;
    uint4  wh0, wh1, wl0, wl1;

    auto loadG = [&](int ch) {
        int ks = (ch * 32) / CIN, c0 = (ch * 32) % CIN;
        int node = ks == 0 ? il0 : (ks == 1 ? il1 : il2);
        const float* s = gBase + (size_t)node * CIN + c0 + cb;
        g0 = *(const float4*)&s[0];  g1 = *(const float4*)&s[4];
        g2 = *(const float4*)&s[8];  g3 = *(const float4*)&s[12];
    };
    auto loadW = [&](int ch) {
        int kk0 = ch * 32;
        if constexpr (OCH_T == 128) {
            const unsigned short* ph = &WHi[(size_t)(och0 + (t & 127)) * K + kk0 + (t >> 7) * 16];
            const unsigned short* pl = &WLo[(size_t)(och0 + (t & 127)) * K + kk0 + (t >> 7) * 16];
            wh0 = *(const uint4*)ph; wh1 = *(const uint4*)(ph + 8);
            wl0 = *(const uint4*)pl; wl1 = *(const uint4*)(pl + 8);
        } else {
            const unsigned short* ph = &WHi[(size_t)(och0 + (t & 63)) * K + kk0 + (t >> 6) * 8];
            const unsigned short* pl = &WLo[(size_t)(och0 + (t & 63)) * K + kk0 + (t >> 6) * 8];
            wh0 = *(const uint4*)ph;
            wl0 = *(const uint4*)pl;
        }
    };
    auto stage = [&](int buf) {
        float4 v0 = g0, v1 = g1, v2 = g2, v3 = g3;
        if (NORM_IN) {
            #define LKY(x) { x = (x - mean) * inv; x = x >= 0.f ? x : 0.01f * x; }
            LKY(v0.x) LKY(v0.y) LKY(v0.z) LKY(v0.w)
            LKY(v1.x) LKY(v1.y) LKY(v1.z) LKY(v1.w)
            LKY(v2.x) LKY(v2.y) LKY(v2.z) LKY(v2.w)
            LKY(v3.x) LKY(v3.y) LKY(v3.z) LKY(v3.w)
            #undef LKY
        }
        uint4 H0, L0, H1, L1;
        split2(v0.x, v0.y, H0.x, L0.x); split2(v0.z, v0.w, H0.y, L0.y);
        split2(v1.x, v1.y, H0.z, L0.z); split2(v1.z, v1.w, H0.w, L0.w);
        split2(v2.x, v2.y, H1.x, L1.x); split2(v2.z, v2.w, H1.y, L1.y);
        split2(v3.x, v3.y, H1.z, L1.z); split2(v3.z, v3.w, H1.w, L1.w);
        unsigned short* gh = &Gh[(buf * 4 + 2 * ghalf) * GP + nodeL * 8];
        unsigned short* gl = &Gl[(buf * 4 + 2 * ghalf) * GP + nodeL * 8];
        *(uint4*)gh = H0; *(uint4*)(gh + GP) = H1;
        *(uint4*)gl = L0; *(uint4*)(gl + GP) = L1;
        if constexpr (OCH_T == 128) {
            unsigned short* wh = &Wh[(buf * 4 + 2 * ghalf) * WP + nodeL * 8];
            unsigned short* wl = &Wl[(buf * 4 + 2 * ghalf) * WP + nodeL * 8];
            *(uint4*)wh = wh0; *(uint4*)(wh + WP) = wh1;
            *(uint4*)wl = wl0; *(uint4*)(wl + WP) = wl1;
        } else {
            unsigned short* wh = &Wh[(buf * 4 + (t >> 6)) * WP + (t & 63) * 8];
            unsigned short* wl = &Wl[(buf * 4 + (t >> 6)) * WP + (t & 63) * 8];
            *(uint4*)wh = wh0;
            *(uint4*)wl = wl0;
        }
    };

    f32x4 acc[4][NI] = {};

    // prologue: stage chunk 0, prefetch chunk 1
    loadG(0); loadW(0);
    stage(0);
    loadG(1); loadW(1);
    __syncthreads();

    for (int ch = 0; ch < NK; ++ch) {
        const int cur = ch & 1;
        if (ch + 1 < NK) {
            stage(cur ^ 1);                              // consumes prefetched regs
            if (ch + 2 < NK) { loadG(ch + 2); loadW(ch + 2); }
        }
        // ---- fragments + MFMA from buf cur ----
        bf16x8 Ah[4], Al[4], Bh[NI], Bl[NI];
        const unsigned short* ga = &Gh[(cur * 4 + l16) * GP + (wm * 64 + l15) * 8];
        const unsigned short* gb = &Gl[(cur * 4 + l16) * GP + (wm * 64 + l15) * 8];
        #pragma unroll
        for (int mi = 0; mi < 4; ++mi) {
            Ah[mi] = *(const bf16x8*)(ga + mi * 128);
            Al[mi] = *(const bf16x8*)(gb + mi * 128);
        }
        const unsigned short* wa = &Wh[(cur * 4 + l16) * WP + (wn * OH + l15) * 8];
        const unsigned short* wb = &Wl[(cur * 4 + l16) * WP + (wn * OH + l15) * 8];
        #pragma unroll
        for (int ni = 0; ni < NI; ++ni) {
            Bh[ni] = *(const bf16x8*)(wa + ni * 128);
            Bl[ni] = *(const bf16x8*)(wb + ni * 128);
        }
        #pragma unroll
        for (int mi = 0; mi < 4; ++mi)
            #pragma unroll
            for (int ni = 0; ni < NI; ++ni) {
                acc[mi][ni] = __builtin_amdgcn_mfma_f32_16x16x32_bf16(Ah[mi], Bh[ni], acc[mi][ni], 0, 0, 0);
                acc[mi][ni] = __builtin_amdgcn_mfma_f32_16x16x32_bf16(Ah[mi], Bl[ni], acc[mi][ni], 0, 0, 0);
                acc[mi][ni] = __builtin_amdgcn_mfma_f32_16x16x32_bf16(Al[mi], Bh[ni], acc[mi][ni], 0, 0, 0);
            }
        __syncthreads();
    }

    // ---- epilogue: bias, store fp32, per-tree stats ----
    float lsum = 0.f, lss = 0.f;
    #pragma unroll
    for (int ni = 0; ni < NI; ++ni) {
        int ol = wn * OH + ni * 16 + l15;
        float bi = bias[och0 + ol];
        #pragma unroll
        for (int mi = 0; mi < 4; ++mi) {
            #pragma unroll
            for (int r = 0; r < 4; ++r) {
                int nl = wm * 64 + mi * 16 + l16 * 4 + r;
                int ng = n0 + nl;
                if (ng <= 511) {
                    float v = acc[mi][ni][r] + bi;
                    out[((size_t)b * 512 + ng) * COUT + och0 + ol] = v;
                    lsum += v; lss += v * v;
                }
            }
        }
    }

    #pragma unroll
    for (int off = 32; off > 0; off >>= 1) {
        lsum += __shfl_down(lsum, off);
        lss  += __shfl_down(lss, off);
    }
    if (lane == 0) { rs[wave] = lsum; rq[wave] = lss; }
    __syncthreads();
    if (t == 0) {
        atomicAdd(&sOut[b * 2],     rs[0] + rs[1] + rs[2] + rs[3]);
        atomicAdd(&sOut[b * 2 + 1], rq[0] + rq[1] + rq[2] + rq[3]);
    }
}

// ---------------- max-pool (with final norm affine) + FC1 + FC2 ----------------
__global__ __launch_bounds__(256) void k_pool_fc(
    const float* __restrict__ x,      // [Bc][512][64] raw conv3 output
    const float* __restrict__ stats,  // [Bc][2]
    const float* __restrict__ Wf1, const float* __restrict__ bf1,
    const float* __restrict__ Wf2, const float* __restrict__ bf2,
    float* __restrict__ outp)
{
    __shared__ float cm[4][64];
    __shared__ float pool[64];
    __shared__ float h[32];
    int b = blockIdx.x, t = threadIdx.x;
    int c = t & 63, g = t >> 6;
    float m = -1e30f;
    for (int n = 1 + g; n <= 511; n += 4)
        m = fmaxf(m, x[((size_t)b * 512 + n) * 64 + c]);
    cm[g][c] = m;
    __syncthreads();
    if (t < 64) {
        float mm = fmaxf(fmaxf(cm[0][t], cm[1][t]), fmaxf(cm[2][t], cm[3][t]));
        mm = fmaxf(mm, 0.f);  // node-0 zero column participates in the max
        float s = stats[b * 2], ss = stats[b * 2 + 1];
        const float nel = 64.f * 512.f;
        float mu  = s / nel;
        float var = (ss - nel * mu * mu) / (nel - 1.f);
        float inv = 1.f / (sqrtf(var) + 1e-5f);
        pool[t] = (mm - mu) * inv;
    }
    __syncthreads();
    if (t < 32) {
        float acc = bf1[t];
        for (int cc = 0; cc < 64; ++cc) acc += pool[cc] * Wf1[t * 64 + cc];
        h[t] = acc >= 0.f ? acc : 0.01f * acc;
    }
    __syncthreads();
    if (t == 0) {
        float acc = bf2[0];
        for (int j = 0; j < 32; ++j) acc += h[j] * Wf2[j];
        outp[b] = acc;
    }
}

extern "C" void kernel_launch(void* const* d_in, const int* in_sizes, int n_in,
                              void* d_out, int out_size, void* d_ws, size_t ws_size,
                              hipStream_t stream)
{
    const float* trees = (const float*)d_in[0];
    const int*   idx32 = (const int*)d_in[1];
    const float* W1  = (const float*)d_in[2];
    const float* b1  = (const float*)d_in[3];
    const float* W2  = (const float*)d_in[4];
    const float* b2  = (const float*)d_in[5];
    const float* W3  = (const float*)d_in[6];
    const float* b3  = (const float*)d_in[7];
    const float* Wf1 = (const float*)d_in[8];
    const float* bf1 = (const float*)d_in[9];
    const float* Wf2 = (const float*)d_in[10];
    const float* bf2 = (const float*)d_in[11];
    float* outp = (float*)d_out;
    char*  ws   = (char*)d_ws;

    // fixed workspace: stats + split weights (bf16)
    float*          stats = (float*)ws;                         // 12288 B
    unsigned short* w1h = (unsigned short*)(ws + 12288);        // 256*384*2 = 196608
    unsigned short* w1l = (unsigned short*)(ws + 208896);       // 196608
    unsigned short* w2h = (unsigned short*)(ws + 405504);       // 128*768*2 = 196608
    unsigned short* w2l = (unsigned short*)(ws + 602112);       // 196608
    unsigned short* w3h = (unsigned short*)(ws + 798720);       // 64*384*2 = 49152
    unsigned short* w3l = (unsigned short*)(ws + 847872);       // 49152
    char* chunkBase = ws + 897024;
    float* s0 = stats, *s1 = stats + 1024, *s2 = stats + 2048;

    // adaptive batch chunking: per-chunk bytes = Bc * (128+256+64)*512*4 = Bc*917504
    const size_t fixedB = 897024;
    int Bc = 512;
    while (Bc > 1 && fixedB + (size_t)Bc * 917504 > ws_size) Bc >>= 1;

    hipMemsetAsync(stats, 0, 12288, stream);
    k_repackW<128, 256><<<384, 256, 0, stream>>>(W1, w1h, w1l);
    k_repackW<256, 128><<<384, 256, 0, stream>>>(W2, w2h, w2l);
    k_repackW<128, 64><<<96, 256, 0, stream>>>(W3, w3h, w3l);

    float* t0   = (float*)chunkBase;                              // Bc*512*128 f32 (also out2)
    float* out1 = (float*)(chunkBase + (size_t)Bc * 262144);      // Bc*512*256 f32
    float* out3 = (float*)(chunkBase + (size_t)Bc * 786432);      // Bc*512*64  f32

    for (int c0 = 0; c0 < 512; c0 += Bc) {
        const float* treesC = trees + (size_t)c0 * 128 * 512;
        const int*   idxC   = idx32 + (size_t)c0 * TRIP;

        k_transpose<<<dim3(8, 1, Bc), 256, 0, stream>>>(treesC, t0);
        k_convmfma<128, 256, 128, false><<<dim3(4, 2, Bc), 256, 0, stream>>>(
            t0, idxC, w1h, w1l, b1, out1, nullptr, s0 + c0 * 2);
        k_zero_row0<<<Bc, 256, 0, stream>>>(out1, t0, out3);
        k_convmfma<256, 128, 128, true><<<dim3(4, 1, Bc), 256, 0, stream>>>(
            out1, idxC, w2h, w2l, b2, t0, s0 + c0 * 2, s1 + c0 * 2);
        k_convmfma<128, 64, 64, true><<<dim3(4, 1, Bc), 256, 0, stream>>>(
            t0, idxC, w3h, w3l, b3, out3, s1 + c0 * 2, s2 + c0 * 2);
        k_pool_fc<<<Bc, 256, 0, stream>>>(out3, s2 + c0 * 2, Wf1, bf1, Wf2, bf2, outp + c0);
    }

    (void)in_sizes; (void)n_in; (void)out_size; (void)ws_size;
}

// Round 9
// 687.935 us; speedup vs baseline: 1.3524x; 1.3524x over previous
//
// v8: tree-affinity XCD swizzle (all blocks of a tree -> same XCD for L2 gather
//     residency), W-fragments direct from global (slice-major, L1-resident;
//     no W in LDS -> 16.6 KB LDS, single-buffer 2-barrier loop), T14 G prefetch.
#include <hip/hip_runtime.h>

#define TRIP 1533   // 3*511

typedef __attribute__((ext_vector_type(8))) short bf16x8;
typedef __attribute__((ext_vector_type(4))) float f32x4;

__device__ __forceinline__ void split2(float a, float b, unsigned& h, unsigned& l) {
    unsigned ba = __float_as_uint(a), bb = __float_as_uint(b);
    unsigned ha = ba & 0xFFFF0000u, hb = bb & 0xFFFF0000u;
    float ra = a - __uint_as_float(ha);
    float rb = b - __uint_as_float(hb);
    h = (ba >> 16) | hb;
    l = (__float_as_uint(ra) >> 16) | (__float_as_uint(rb) & 0xFFFF0000u);
}

// ---- W repack+split, slice-major: Wr[(kk/8)*COUT + o][kk%8], kk = ks*CIN+c ----
template<int CIN, int COUT>
__global__ void k_repackW(const float* __restrict__ W,
                          unsigned short* __restrict__ Hi, unsigned short* __restrict__ Lo) {
    int id = blockIdx.x * 256 + threadIdx.x;
    if (id >= 3 * CIN * COUT) return;
    int o = id / (3 * CIN), kk = id % (3 * CIN);
    int ks = kk / CIN, c = kk % CIN;
    float v = W[(o * CIN + c) * 3 + ks];
    unsigned b = __float_as_uint(v);
    unsigned h = b & 0xFFFF0000u;
    float r = v - __uint_as_float(h);
    size_t dst = ((size_t)(kk >> 3) * COUT + o) * 8 + (kk & 7);
    Hi[dst] = (unsigned short)(b >> 16);
    Lo[dst] = (unsigned short)(__float_as_uint(r) >> 16);
}

// ---------------- transpose trees [Bc][128][512] -> t0 [Bc][512][128] ----------------
__global__ void k_transpose(const float* __restrict__ in, float* __restrict__ out) {
    __shared__ float tl[64][129];
    int b = blockIdx.z, n0 = blockIdx.x * 64, t = threadIdx.x;
    int n = t & 63;
    for (int c = t >> 6; c < 128; c += 4)
        tl[n][c] = in[((size_t)b * 128 + c) * 512 + n0 + n];
    __syncthreads();
    int cq = t & 31;
    for (int nr = t >> 5; nr < 64; nr += 8) {
        float4 v = { tl[nr][cq*4+0], tl[nr][cq*4+1], tl[nr][cq*4+2], tl[nr][cq*4+3] };
        *(float4*)&out[((size_t)b * 512 + n0 + nr) * 128 + cq * 4] = v;
    }
}

// ---------------- zero node-0 row of activation buffers ----------------
__global__ void k_zero_row0(float* __restrict__ o1, float* __restrict__ o2, float* __restrict__ o3) {
    int b = blockIdx.x, t = threadIdx.x;
    if (t < 256) o1[(size_t)b * 512 * 256 + t] = 0.f;
    if (t < 128) o2[(size_t)b * 512 * 128 + t] = 0.f;
    if (t < 64)  o3[(size_t)b * 512 * 64  + t] = 0.f;
}

// ---------------- MFMA conv: Out[b][n][o] = sum_kk f(G)[n][kk] * W[kk][o] ----------------
// Block tile 128 nodes x OCH_T; 4 waves (2 node x 2 och), wave tile 64 x OCH_T/2.
// G staged in LDS (slice-major, conflict-free, 16.6 KB); W frags read directly
// from global (slice-major repack; L1-resident). Tree-affinity XCD swizzle.
template<int CIN, int COUT, int OCH_T, bool NORM_IN>
__global__ __launch_bounds__(256, 3) void k_convmfma(
    const float* __restrict__ xin, const int* __restrict__ idx,
    const unsigned short* __restrict__ WHi, const unsigned short* __restrict__ WLo,
    const float* __restrict__ bias, float* __restrict__ out,
    const float* __restrict__ sIn, float* __restrict__ sOut)
{
    constexpr int K  = 3 * CIN;
    constexpr int NK = K / 32;
    constexpr int NI = OCH_T / 32;   // B frags per wave
    constexpr int OH = OCH_T / 2;    // wave och tile
    constexpr int GP = 128 * 8 + 8;  // G slice pitch (ushorts), 16B stagger
    constexpr int GY = COUT / OCH_T; // grid.y
    constexpr int P  = 4 * GY;       // blocks per tree
    constexpr int G8 = 8 * P;        // dispatch group

    __shared__ unsigned short Gh[4 * GP], Gl[4 * GP];
    __shared__ float rs[4], rq[4];

    // ---- tree-affinity swizzle: all P blocks of a tree share (f % 8) -> same XCD ----
    int b, bx, by;
    {
        const int gz = gridDim.z;
        int f = (blockIdx.z * GY + blockIdx.y) * 4 + blockIdx.x;  // dispatch order
        if ((gz & 7) == 0) {
            int g = f / G8, w = f - g * G8;
            b = g * 8 + (w & 7);
            int blk = w >> 3;
            bx = blk & 3; by = blk >> 2;
        } else { b = blockIdx.z; bx = blockIdx.x; by = blockIdx.y; }
    }
    const int och0 = by * OCH_T;
    const int n0   = 1 + bx * 128;
    const int t    = threadIdx.x;
    const int lane = t & 63, wave = t >> 6;
    const int wm = wave >> 1, wn = wave & 1;
    const int l15 = lane & 15, l16 = lane >> 4;

    float mean = 0.f, inv = 1.f;
    if (NORM_IN) {
        float s = sIn[b * 2], ss = sIn[b * 2 + 1];
        const float nel = (float)(CIN * 512);
        float mu  = s / nel;
        float var = (ss - nel * mu * mu) / (nel - 1.f);
        mean = mu; inv = 1.f / (sqrtf(var) + 1e-5f);
    }

    // staging roles: node = t&127, k-half = t>>7 (16 floats each)
    const int nodeL = t & 127, ghalf = t >> 7, cb = ghalf * 16;
    int il0 = 0, il1 = 0, il2 = 0;
    if (n0 + nodeL <= 511) {
        const int* ip = &idx[b * TRIP + 3 * (n0 - 1 + nodeL)];
        il0 = ip[0]; il1 = ip[1]; il2 = ip[2];
    }
    const float* gBase = &xin[(size_t)b * 512 * CIN + cb];

    // B-frag global base (slice-major): slice = kk0/8 + l16, och = och0+wn*OH+ni*16+l15
    const unsigned short* wbH = WHi + ((size_t)l16 * COUT + och0 + wn * OH + l15) * 8;
    const unsigned short* wbL = WLo + ((size_t)l16 * COUT + och0 + wn * OH + l15) * 8;

    float4 g0, g1, g2, g3;
    auto loadG = [&](int ch) {
        int ks = (ch * 32) / CIN, c0 = (ch * 32) % CIN;
        int node = ks == 0 ? il0 : (ks == 1 ? il1 : il2);
        const float* s = gBase + (size_t)node * CIN + c0;
        g0 = *(const float4*)&s[0];  g1 = *(const float4*)&s[4];
        g2 = *(const float4*)&s[8];  g3 = *(const float4*)&s[12];
    };

    f32x4 acc[4][NI] = {};
    loadG(0);

    for (int ch = 0; ch < NK; ++ch) {
        __syncthreads();   // waves done reading previous chunk's G
        // ---- transform + split + LDS store ----
        {
            float4 v0 = g0, v1 = g1, v2 = g2, v3 = g3;
            if (NORM_IN) {
                #define LKY(x) { x = (x - mean) * inv; x = x >= 0.f ? x : 0.01f * x; }
                LKY(v0.x) LKY(v0.y) LKY(v0.z) LKY(v0.w)
                LKY(v1.x) LKY(v1.y) LKY(v1.z) LKY(v1.w)
                LKY(v2.x) LKY(v2.y) LKY(v2.z) LKY(v2.w)
                LKY(v3.x) LKY(v3.y) LKY(v3.z) LKY(v3.w)
                #undef LKY
            }
            uint4 H0, L0, H1, L1;
            split2(v0.x, v0.y, H0.x, L0.x); split2(v0.z, v0.w, H0.y, L0.y);
            split2(v1.x, v1.y, H0.z, L0.z); split2(v1.z, v1.w, H0.w, L0.w);
            split2(v2.x, v2.y, H1.x, L1.x); split2(v2.z, v2.w, H1.y, L1.y);
            split2(v3.x, v3.y, H1.z, L1.z); split2(v3.z, v3.w, H1.w, L1.w);
            unsigned short* gh = &Gh[(2 * ghalf) * GP + nodeL * 8];
            unsigned short* gl = &Gl[(2 * ghalf) * GP + nodeL * 8];
            *(uint4*)gh = H0; *(uint4*)(gh + GP) = H1;
            *(uint4*)gl = L0; *(uint4*)(gl + GP) = L1;
        }
        // ---- T14: next chunk's gather issued now, lands under barrier+MFMA ----
        if (ch + 1 < NK) loadG(ch + 1);
        // ---- B frags for this chunk straight from global (L1-resident) ----
        bf16x8 Bh[NI], Bl[NI];
        {
            const size_t so = (size_t)(ch * 4) * COUT * 8;   // slice advance kk0/8 = 4*ch
            #pragma unroll
            for (int ni = 0; ni < NI; ++ni) {
                Bh[ni] = *(const bf16x8*)(wbH + so + ni * 128);
                Bl[ni] = *(const bf16x8*)(wbL + so + ni * 128);
            }
        }
        __syncthreads();   // G staged

        // ---- A frags + MFMA ----
        bf16x8 Ah[4], Al[4];
        const unsigned short* ga = &Gh[l16 * GP + (wm * 64 + l15) * 8];
        const unsigned short* gb = &Gl[l16 * GP + (wm * 64 + l15) * 8];
        #pragma unroll
        for (int mi = 0; mi < 4; ++mi) {
            Ah[mi] = *(const bf16x8*)(ga + mi * 128);
            Al[mi] = *(const bf16x8*)(gb + mi * 128);
        }
        #pragma unroll
        for (int mi = 0; mi < 4; ++mi)
            #pragma unroll
            for (int ni = 0; ni < NI; ++ni) {
                acc[mi][ni] = __builtin_amdgcn_mfma_f32_16x16x32_bf16(Ah[mi], Bh[ni], acc[mi][ni], 0, 0, 0);
                acc[mi][ni] = __builtin_amdgcn_mfma_f32_16x16x32_bf16(Ah[mi], Bl[ni], acc[mi][ni], 0, 0, 0);
                acc[mi][ni] = __builtin_amdgcn_mfma_f32_16x16x32_bf16(Al[mi], Bh[ni], acc[mi][ni], 0, 0, 0);
            }
    }

    // ---- epilogue: bias, store fp32, per-tree stats ----
    float lsum = 0.f, lss = 0.f;
    #pragma unroll
    for (int ni = 0; ni < NI; ++ni) {
        int ol = wn * OH + ni * 16 + l15;
        float bi = bias[och0 + ol];
        #pragma unroll
        for (int mi = 0; mi < 4; ++mi) {
            #pragma unroll
            for (int r = 0; r < 4; ++r) {
                int nl = wm * 64 + mi * 16 + l16 * 4 + r;
                int ng = n0 + nl;
                if (ng <= 511) {
                    float v = acc[mi][ni][r] + bi;
                    out[((size_t)b * 512 + ng) * COUT + och0 + ol] = v;
                    lsum += v; lss += v * v;
                }
            }
        }
    }

    #pragma unroll
    for (int off = 32; off > 0; off >>= 1) {
        lsum += __shfl_down(lsum, off);
        lss  += __shfl_down(lss, off);
    }
    if (lane == 0) { rs[wave] = lsum; rq[wave] = lss; }
    __syncthreads();
    if (t == 0) {
        atomicAdd(&sOut[b * 2],     rs[0] + rs[1] + rs[2] + rs[3]);
        atomicAdd(&sOut[b * 2 + 1], rq[0] + rq[1] + rq[2] + rq[3]);
    }
}

// ---------------- max-pool (with final norm affine) + FC1 + FC2 ----------------
__global__ __launch_bounds__(256) void k_pool_fc(
    const float* __restrict__ x,      // [Bc][512][64] raw conv3 output
    const float* __restrict__ stats,  // [Bc][2]
    const float* __restrict__ Wf1, const float* __restrict__ bf1,
    const float* __restrict__ Wf2, const float* __restrict__ bf2,
    float* __restrict__ outp)
{
    __shared__ float cm[4][64];
    __shared__ float pool[64];
    __shared__ float h[32];
    int b = blockIdx.x, t = threadIdx.x;
    int c = t & 63, g = t >> 6;
    float m = -1e30f;
    for (int n = 1 + g; n <= 511; n += 4)
        m = fmaxf(m, x[((size_t)b * 512 + n) * 64 + c]);
    cm[g][c] = m;
    __syncthreads();
    if (t < 64) {
        float mm = fmaxf(fmaxf(cm[0][t], cm[1][t]), fmaxf(cm[2][t], cm[3][t]));
        mm = fmaxf(mm, 0.f);  // node-0 zero column participates in the max
        float s = stats[b * 2], ss = stats[b * 2 + 1];
        const float nel = 64.f * 512.f;
        float mu  = s / nel;
        float var = (ss - nel * mu * mu) / (nel - 1.f);
        float inv = 1.f / (sqrtf(var) + 1e-5f);
        pool[t] = (mm - mu) * inv;
    }
    __syncthreads();
    if (t < 32) {
        float acc = bf1[t];
        for (int cc = 0; cc < 64; ++cc) acc += pool[cc] * Wf1[t * 64 + cc];
        h[t] = acc >= 0.f ? acc : 0.01f * acc;
    }
    __syncthreads();
    if (t == 0) {
        float acc = bf2[0];
        for (int j = 0; j < 32; ++j) acc += h[j] * Wf2[j];
        outp[b] = acc;
    }
}

extern "C" void kernel_launch(void* const* d_in, const int* in_sizes, int n_in,
                              void* d_out, int out_size, void* d_ws, size_t ws_size,
                              hipStream_t stream)
{
    const float* trees = (const float*)d_in[0];
    const int*   idx32 = (const int*)d_in[1];
    const float* W1  = (const float*)d_in[2];
    const float* b1  = (const float*)d_in[3];
    const float* W2  = (const float*)d_in[4];
    const float* b2  = (const float*)d_in[5];
    const float* W3  = (const float*)d_in[6];
    const float* b3  = (const float*)d_in[7];
    const float* Wf1 = (const float*)d_in[8];
    const float* bf1 = (const float*)d_in[9];
    const float* Wf2 = (const float*)d_in[10];
    const float* bf2 = (const float*)d_in[11];
    float* outp = (float*)d_out;
    char*  ws   = (char*)d_ws;

    // fixed workspace: stats + split weights (bf16, slice-major)
    float*          stats = (float*)ws;                         // 12288 B
    unsigned short* w1h = (unsigned short*)(ws + 12288);        // 256*384*2 = 196608
    unsigned short* w1l = (unsigned short*)(ws + 208896);       // 196608
    unsigned short* w2h = (unsigned short*)(ws + 405504);       // 128*768*2 = 196608
    unsigned short* w2l = (unsigned short*)(ws + 602112);       // 196608
    unsigned short* w3h = (unsigned short*)(ws + 798720);       // 64*384*2 = 49152
    unsigned short* w3l = (unsigned short*)(ws + 847872);       // 49152
    char* chunkBase = ws + 897024;
    float* s0 = stats, *s1 = stats + 1024, *s2 = stats + 2048;

    // adaptive batch chunking: per-chunk bytes = Bc * (128+256+64)*512*4 = Bc*917504
    const size_t fixedB = 897024;
    int Bc = 512;
    while (Bc > 1 && fixedB + (size_t)Bc * 917504 > ws_size) Bc >>= 1;

    hipMemsetAsync(stats, 0, 12288, stream);
    k_repackW<128, 256><<<384, 256, 0, stream>>>(W1, w1h, w1l);
    k_repackW<256, 128><<<384, 256, 0, stream>>>(W2, w2h, w2l);
    k_repackW<128, 64><<<96, 256, 0, stream>>>(W3, w3h, w3l);

    float* t0   = (float*)chunkBase;                              // Bc*512*128 f32 (also out2)
    float* out1 = (float*)(chunkBase + (size_t)Bc * 262144);      // Bc*512*256 f32
    float* out3 = (float*)(chunkBase + (size_t)Bc * 786432);      // Bc*512*64  f32

    for (int c0 = 0; c0 < 512; c0 += Bc) {
        const float* treesC = trees + (size_t)c0 * 128 * 512;
        const int*   idxC   = idx32 + (size_t)c0 * TRIP;

        k_transpose<<<dim3(8, 1, Bc), 256, 0, stream>>>(treesC, t0);
        k_convmfma<128, 256, 128, false><<<dim3(4, 2, Bc), 256, 0, stream>>>(
            t0, idxC, w1h, w1l, b1, out1, nullptr, s0 + c0 * 2);
        k_zero_row0<<<Bc, 256, 0, stream>>>(out1, t0, out3);
        k_convmfma<256, 128, 128, true><<<dim3(4, 1, Bc), 256, 0, stream>>>(
            out1, idxC, w2h, w2l, b2, t0, s0 + c0 * 2, s1 + c0 * 2);
        k_convmfma<128, 64, 64, true><<<dim3(4, 1, Bc), 256, 0, stream>>>(
            t0, idxC, w3h, w3l, b3, out3, s1 + c0 * 2, s2 + c0 * 2);
        k_pool_fc<<<Bc, 256, 0, stream>>>(out3, s2 + c0 * 2, Wf1, bf1, Wf2, bf2, outp + c0);
    }

    (void)in_sizes; (void)n_in; (void)out_size; (void)ws_size;
}